// Round 5
// baseline (3640.147 us; speedup 1.0000x reference)
//
#include <hip/hip_runtime.h>

// Orient_Conv: 3x3 orientation-gated conv, 4 orientations + per-pixel argmax.
// B=4, CIN=COUT=32, H=W=128, pad=1.
//
// Gate identity (C=cos(wr), S=sin(wr), r0=cos(th), r1=sin(th)):
//   u = C*r0+S*r1, vv = C*r1-S*r0
//   gates: o0=relu(u), o1=relu(vv), o2=relu(-u), o3=relu(-vv)
//   products: t0=f*relu(u), t1=f*relu(vv), t2 = t0 - f*u (=f*relu(-u)),
//             t3 = t1 - f*vv  -> 14-op packed core, 2 px/v2f.
// Rotated weights at tap (i,j): w0=w[i][j], w1=w[2-j][i], w2=w[2-i][2-j],
//   w3=w[j][2-i].
//
// R15 = R13 base (reg-staged LDS writes, double-buffer, 4 barriers, XCD
// swizzle; 209 us verified) + RA/RB ds_read row-prefetch, register-solvent.
// R14 post-mortem: WRITE_SIZE 1.42 GB = scratch spill (pipeline state ~140
// regs vs the 128 cap of launch_bounds(512,4); allocator spilled the
// ping-pong structs inside the 96-step loop) plus 9x read amplification
// from uncoalesced 4B global_load_lds. Both removed here:
//  (a) keep R13's staging (tF/tA/tB regs -> masked ds_write), no DMA;
//  (b) RA/RB row ping-pong: row s+1's 6 ds_read_b128 issue (pinned with
//      sched_group_barrier(DS_READ,6)) while row s computes -> counted
//      lgkmcnt with a full ~336-cycle row of compute slack;
//  (c) FUND the +48 VGPR: drop the WA/WB weight ping-pong (-36; weights
//      load just-in-time per step, 6 pinned VMEM loads, tab is L2-hot and
//      R11->R12 showed W-pipelining was only worth ~6 us), drop sidx[]
//      (recompute tid+k*512) and msk[] (4-bit okbits + cndmask) (-7).
//      Est ~110 VGPR <= 128 -> launch_bounds(512,4), 2 blocks/CU, no spill.
// Accumulation order unchanged -> output matches R13.

typedef float v2f __attribute__((ext_vector_type(2)));

#define B_    4
#define CIN_  32
#define COUT_ 32
#define H_    128
#define W_    128
#define HW_   (H_ * W_)
#define OUTSZ_ (B_ * COUT_ * H_ * W_)

// tab layout: [cc][tap][oc][8] = {C,S,w0,w1,w2,w3,0,0}; 294912 B
__global__ __launch_bounds__(256)
void build_wtab(const float* __restrict__ w, const float* __restrict__ wr,
                float* __restrict__ tab)
{
    int idx = blockIdx.x * 256 + threadIdx.x;   // ((cc*9+tap)<<5)|oc
    if (idx >= CIN_ * 9 * COUT_) return;        // 9216
    int oc  = idx & 31;
    int t2  = idx >> 5;
    int tap = t2 % 9;
    int cc  = t2 / 9;
    int i = tap / 3, j = tap - i * 3;
    int base = (oc * CIN_ + cc) * 9;
    float w0 = w[base + i * 3 + j];
    float w1 = w[base + (2 - j) * 3 + i];
    float w2 = w[base + (2 - i) * 3 + (2 - j)];
    float w3 = w[base + j * 3 + (2 - i)];
    float S, C;
    sincosf(wr[base + i * 3 + j], &S, &C);
    float* dst = tab + (size_t)idx * 8;
    dst[0] = C;  dst[1] = S;
    dst[2] = w0; dst[3] = w1;
    dst[4] = w2; dst[5] = w3;
    dst[6] = 0.0f; dst[7] = 0.0f;
}

#define NC_    8                      // channels staged per buffer
#define NG_    (CIN_ / NC_)           // 4 groups
#define ROWF_  68                     // floats per row = 34 pairs x 2
#define CLSTR_ (3 * ROWF_)            // 204 floats per staged channel
#define USED_  (NC_ * CLSTR_)         // 1632 slots per plane
#define PLANE_ 1636                   // plane stride (pad; 1636%32=4)
#define NBUF_  (3 * PLANE_)           // floats per buffer (f,r0,r1 planes)

struct WRow { float4 a0, a1, a2; float2 b0, b1, b2; };       // 18 floats
struct RRow { float4 f0, f1, a0, a1, b0, b1; };              // 24 floats

// Just-in-time weight row load for COMPUTED row (CCL, CII): 6 words for
// taps 3*CII..3*CII+2 of channel g*8+CCL, pinned at the step top. Base is
// per-step; imm offsets 0/+1024/+2048 B within the 13-bit signed range.
#define LOAD_W(Wd, CCL, CII) do {                                           \
    const float* _wp = wgptr + ((CCL) * 9 + (CII) * 3) * 256;               \
    (Wd).a0 = *reinterpret_cast<const float4*>(_wp);                        \
    (Wd).b0 = *reinterpret_cast<const float2*>(_wp + 4);                    \
    (Wd).a1 = *reinterpret_cast<const float4*>(_wp + 256);                  \
    (Wd).b1 = *reinterpret_cast<const float2*>(_wp + 260);                  \
    (Wd).a2 = *reinterpret_cast<const float4*>(_wp + 512);                  \
    (Wd).b2 = *reinterpret_cast<const float2*>(_wp + 516);                  \
    __builtin_amdgcn_sched_group_barrier(0x020, 6, 0); /* 6 VMEM reads */   \
} while (0)

// Load one LDS row (6 x ds_read_b128) into an RRow, pinned at issue point.
#define RLOAD(Rd, RB_, CL, II) do {                                         \
    const float* _rp = (RB_) + (CL) * CLSTR_ + (II) * ROWF_ + (p << 1);     \
    (Rd).f0 = *reinterpret_cast<const float4*>(_rp);                        \
    (Rd).f1 = *reinterpret_cast<const float4*>(_rp + 4);                    \
    (Rd).a0 = *reinterpret_cast<const float4*>(_rp + PLANE_);               \
    (Rd).a1 = *reinterpret_cast<const float4*>(_rp + PLANE_ + 4);           \
    (Rd).b0 = *reinterpret_cast<const float4*>(_rp + 2 * PLANE_);           \
    (Rd).b1 = *reinterpret_cast<const float4*>(_rp + 2 * PLANE_ + 4);       \
    __builtin_amdgcn_sched_group_barrier(0x100, 6, 0); /* 6 DS reads */     \
} while (0)

#define CORE_TAP(W4, W2, JJ) do {                                           \
    v2f _C2  = {(W4).x, (W4).x};                                            \
    v2f _S2  = {(W4).y, (W4).y};                                            \
    v2f _w0  = {(W4).z, (W4).z};                                            \
    v2f _w1  = {(W4).w, (W4).w};                                            \
    v2f _w2  = {(W2).x, (W2).x};                                            \
    v2f _w3  = {(W2).y, (W2).y};                                            \
    _Pragma("unroll")                                                       \
    for (int _q = 0; _q < 2; ++_q) {                                        \
        v2f _f  = _fP[_q + (JJ)];                                           \
        v2f _r0 = _aP[_q + (JJ)];                                           \
        v2f _r1 = _bP[_q + (JJ)];                                           \
        v2f _m1 = _S2 * _r1;                                                \
        v2f _u  = __builtin_elementwise_fma(_C2, _r0, _m1);                 \
        v2f _m2 = _S2 * _r0;                                                \
        v2f _vv = __builtin_elementwise_fma(_C2, _r1, -_m2);                \
        v2f _g0 = __builtin_elementwise_max(_u,  (v2f)(0.0f));              \
        v2f _g1 = __builtin_elementwise_max(_vv, (v2f)(0.0f));              \
        v2f _t0 = _f * _g0;                                                 \
        v2f _t1 = _f * _g1;                                                 \
        v2f _t2 = __builtin_elementwise_fma(_f, -_u,  _t0);                 \
        v2f _t3 = __builtin_elementwise_fma(_f, -_vv, _t1);                 \
        acc[_q][0] = __builtin_elementwise_fma(_t0, _w0, acc[_q][0]);       \
        acc[_q][1] = __builtin_elementwise_fma(_t1, _w1, acc[_q][1]);       \
        acc[_q][2] = __builtin_elementwise_fma(_t2, _w2, acc[_q][2]);       \
        acc[_q][3] = __builtin_elementwise_fma(_t3, _w3, acc[_q][3]);       \
    }                                                                       \
} while (0)

#define COMPUTE_R(Wr, Rs) do {                                              \
    v2f _fP[4] = {{(Rs).f0.x,(Rs).f0.y},{(Rs).f0.z,(Rs).f0.w},              \
                  {(Rs).f1.x,(Rs).f1.y},{(Rs).f1.z,(Rs).f1.w}};             \
    v2f _aP[4] = {{(Rs).a0.x,(Rs).a0.y},{(Rs).a0.z,(Rs).a0.w},              \
                  {(Rs).a1.x,(Rs).a1.y},{(Rs).a1.z,(Rs).a1.w}};             \
    v2f _bP[4] = {{(Rs).b0.x,(Rs).b0.y},{(Rs).b0.z,(Rs).b0.w},              \
                  {(Rs).b1.x,(Rs).b1.y},{(Rs).b1.z,(Rs).b1.w}};             \
    CORE_TAP((Wr).a0, (Wr).b0, 0);                                          \
    CORE_TAP((Wr).a1, (Wr).b1, 1);                                          \
    CORE_TAP((Wr).a2, (Wr).b2, 2);                                          \
} while (0)

// STEP: JIT-load this step's weights, prefetch NEXT row (LCL,LII) into Rld,
// compute CURRENT row (CCL,CII) from Ruse.
#define STEP(Rld, Ruse, LCL, LII, CCL, CII) do {                            \
    WRow _W;                                                                \
    LOAD_W(_W, CCL, CII);                                                   \
    RLOAD(Rld, cur, LCL, LII);                                              \
    COMPUTE_R(_W, Ruse);                                                    \
} while (0)

#define STEP_LAST(Ruse) do {                                                \
    WRow _W;                                                                \
    LOAD_W(_W, 7, 2);                                                       \
    COMPUTE_R(_W, Ruse);                                                    \
} while (0)

// Issue the 12 global loads for group GI into tF/tA/tB (in flight across a
// full compute phase before STAGE_WRITE consumes them).
#define STAGE_LOAD(GI) do {                                                 \
    const int _gb = chanBase + (GI) * (NC_ * HW_);                          \
    const float* _fb = f  + _gb;                                            \
    const float* _ab = r0 + _gb;                                            \
    const float* _bb = r1 + _gb;                                            \
    _Pragma("unroll")                                                       \
    for (int _k = 0; _k < 3; ++_k) {                                        \
        tF[_k] = _fb[goff[_k]]; tA[_k] = _ab[goff[_k]]; tB[_k] = _bb[goff[_k]]; \
    }                                                                       \
    if (have3) { tF[3] = _fb[goff[3]]; tA[3] = _ab[goff[3]]; tB[3] = _bb[goff[3]]; } \
} while (0)

// Masked ds_write of the staged group; slot index recomputed (tid + k*512),
// OOB-halo lanes write 0 via cndmask on okbits.
#define STAGE_WRITE(DST) do {                                               \
    float* _d = (DST);                                                      \
    _Pragma("unroll")                                                       \
    for (int _k = 0; _k < 3; ++_k) {                                        \
        const int _s = tid + (_k << 9);                                     \
        const bool _ok = (okbits >> _k) & 1;                                \
        _d[             _s] = _ok ? tF[_k] : 0.0f;                          \
        _d[PLANE_     + _s] = _ok ? tA[_k] : 0.0f;                          \
        _d[2 * PLANE_ + _s] = _ok ? tB[_k] : 0.0f;                          \
    }                                                                       \
    if (have3) {                                                            \
        const int _s = tid + 1536;                                          \
        const bool _ok = (okbits >> 3) & 1;                                 \
        _d[             _s] = _ok ? tF[3] : 0.0f;                           \
        _d[PLANE_     + _s] = _ok ? tA[3] : 0.0f;                           \
        _d[2 * PLANE_ + _s] = _ok ? tB[3] : 0.0f;                           \
    }                                                                       \
} while (0)

__global__ __launch_bounds__(512, 4)
void orient_conv_kernel(const float* __restrict__ f,
                        const float* __restrict__ r0,
                        const float* __restrict__ r1,
                        const float* __restrict__ tab,
                        float* __restrict__ out)
{
    // Double-buffered: planes 0=f, 1=r0, 2=r1 per buffer. Within plane:
    // [cl(8)][row(3)][pairslot(68)]; pairslot = c01*2 + s holds col c01+32*s.
    __shared__ float sm[2 * NBUF_];    // 39264 B

    const int tid   = threadIdx.x;
    const int oc    = tid & 31;
    const int pxg   = tid >> 5;            // 0..15
    const int p     = pxg << 1;            // even pair index 0..30
    // XCD-aware bijective swizzle: 8 XCDs, nwg=1024, 1024%8==0.
    const int obid  = blockIdx.x;
    const int bid   = (obid & 7) * ((B_ * H_ * 2) >> 3) + (obid >> 3);
    const int b     = bid >> 8;
    const int rem   = bid & 255;
    const int h     = rem >> 1;
    const int wbase = (rem & 1) << 6;      // 0 or 64

    // ---- staging descriptors: per-lane global offset + validity bits ----
    int      goff[4];
    unsigned okbits = 0;
#pragma unroll
    for (int k = 0; k < 4; ++k) {
        int s = tid + (k << 9);
        int ok = 0, go = 0;
        if (s < USED_) {
            int cl  = s / CLSTR_;
            int r2  = s - cl * CLSTR_;
            int row = r2 / ROWF_;
            int q2  = r2 - row * ROWF_;     // 0..67
            int col = (q2 >> 1) + ((q2 & 1) << 5);   // c01 + 32*s -> 0..65
            int gh = h + row - 1;
            int gw = wbase + col - 1;
            ok = ((unsigned)gh < (unsigned)H_) & ((unsigned)gw < (unsigned)W_);
            go = ok ? (cl * HW_ + gh * W_ + gw) : 0;
        }
        goff[k] = go;
        okbits |= (unsigned)ok << k;
    }
    const bool have3 = tid < 96;           // round-3 slots 1536..1631
    const int chanBase = b * (CIN_ * HW_);

    v2f acc[2][4];                     // [pair q][orient]; elems = px, px+32
#pragma unroll
    for (int q = 0; q < 2; ++q)
#pragma unroll
        for (int o = 0; o < 4; ++o) acc[q][o] = (v2f)(0.0f);

    // ---- prologue staging: g0 -> buf0; g1 loads in flight ----
    float tF[4], tA[4], tB[4];
    STAGE_LOAD(0);
    STAGE_WRITE(sm);                   // vmcnt covered by data dependence
    STAGE_LOAD(1);
    __syncthreads();

#pragma unroll 1
    for (int g = 0; g < NG_; ++g) {
        const float* cur = sm + (g & 1) * NBUF_;
        const float* wgptr = tab + (size_t)oc * 8 + (size_t)g * (NC_ * 9 * 256);
        RRow RA, RB;

        RLOAD(RA, cur, 0, 0);          // first row of this group

        // ---- 24 row-steps; R ping-pongs one row ahead, W loads JIT ----
        STEP(RB, RA, 0, 1, 0, 0);
        STEP(RA, RB, 0, 2, 0, 1);
        STEP(RB, RA, 1, 0, 0, 2);
        STEP(RA, RB, 1, 1, 1, 0);
        STEP(RB, RA, 1, 2, 1, 1);
        STEP(RA, RB, 2, 0, 1, 2);
        STEP(RB, RA, 2, 1, 2, 0);
        STEP(RA, RB, 2, 2, 2, 1);
        STEP(RB, RA, 3, 0, 2, 2);
        STEP(RA, RB, 3, 1, 3, 0);
        STEP(RB, RA, 3, 2, 3, 1);
        STEP(RA, RB, 4, 0, 3, 2);
        STEP(RB, RA, 4, 1, 4, 0);
        STEP(RA, RB, 4, 2, 4, 1);
        STEP(RB, RA, 5, 0, 4, 2);
        STEP(RA, RB, 5, 1, 5, 0);
        STEP(RB, RA, 5, 2, 5, 1);
        STEP(RA, RB, 6, 0, 5, 2);
        STEP(RB, RA, 6, 1, 6, 0);
        STEP(RA, RB, 6, 2, 6, 1);
        STEP(RB, RA, 7, 0, 6, 2);
        STEP(RA, RB, 7, 1, 7, 0);
        STEP(RB, RA, 7, 2, 7, 1);
        STEP_LAST(RB);

        // ---- stage group g+1 into the other buffer, prefetch g+2 ----
        if (g + 1 < NG_) {
            float* wbuf = sm + ((g + 1) & 1) * NBUF_;
            STAGE_WRITE(wbuf);         // waits on loads issued one phase ago
            if (g + 2 < NG_) STAGE_LOAD(g + 2);
            __syncthreads();           // one barrier per group (4 total)
        }
    }

    // ---- epilogue: max/argmax over orientations (first-max tie-break) ----
    const float cosv[4] = {1.0f, -4.37113883e-08f, -1.0f, 1.19248806e-08f};
    const float sinv[4] = {0.0f, 1.0f, -8.74227766e-08f, -1.0f};
#pragma unroll
    for (int q = 0; q < 2; ++q) {
#pragma unroll
        for (int k = 0; k < 2; ++k) {
            int wcol = wbase + p + q + (k << 5);
            float a0 = acc[q][0][k], a1 = acc[q][1][k];
            float a2 = acc[q][2][k], a3 = acc[q][3][k];
            float best = a0; int bi = 0;
            if (a1 > best) { best = a1; bi = 1; }
            if (a2 > best) { best = a2; bi = 2; }
            if (a3 > best) { best = a3; bi = 3; }
            size_t o = ((size_t)(b * COUT_ + oc) * H_ + h) * W_ + wcol;
            out[o]              = best;
            out[o + OUTSZ_]     = cosv[bi];
            out[o + 2 * OUTSZ_] = sinv[bi];
        }
    }
}

extern "C" void kernel_launch(void* const* d_in, const int* in_sizes, int n_in,
                              void* d_out, int out_size, void* d_ws, size_t ws_size,
                              hipStream_t stream)
{
    const float* f  = (const float*)d_in[0];
    const float* r0 = (const float*)d_in[1];
    const float* r1 = (const float*)d_in[2];
    const float* w  = (const float*)d_in[3];
    const float* wr = (const float*)d_in[4];
    float* out = (float*)d_out;
    float* tab = (float*)d_ws;    // 294912 B

    build_wtab<<<dim3(36), dim3(256), 0, stream>>>(w, wr, tab);
    orient_conv_kernel<<<dim3(B_ * H_ * 2), dim3(512), 0, stream>>>(
        f, r0, r1, tab, out);
}

// Round 6
// 3585.483 us; speedup vs baseline: 1.0152x; 1.0152x over previous
//
#include <hip/hip_runtime.h>

// Orient_Conv: 3x3 orientation-gated conv, 4 orientations + per-pixel argmax.
// B=4, CIN=COUT=32, H=W=128, pad=1.
//
// Gate identity (C=cos(wr), S=sin(wr), r0=cos(th), r1=sin(th)):
//   u = C*r0+S*r1, vv = C*r1-S*r0
//   gates: o0=relu(u), o1=relu(vv), o2=relu(-u), o3=relu(-vv)
//   products: t0=f*relu(u), t1=f*relu(vv), t2 = t0 - f*u (=f*relu(-u)),
//             t3 = t1 - f*vv  -> 14-op packed core, 2 px/v2f.
// Rotated weights at tap (i,j): w0=w[i][j], w1=w[2-j][i], w2=w[2-i][2-j],
//   w3=w[j][2-i].
//
// R16 = R15 with the REAL register budget. R14/R15 post-mortem: both used
// __launch_bounds__(512,4) and both compiled to exactly VGPR=64 with
// massive scratch traffic (R15: WRITE 7.6 GB, VALUBusy 4%). On this
// toolchain the 2nd launch_bounds arg behaves CUDA-style (min BLOCKS/CU):
// 4 blocks x 8 waves / 4 SIMDs = 8 waves/EU -> 512-reg pool / 8 = 64-reg
// cap, which strangled the ~113-reg pipeline (acc 16 + RA/RB 48 + WRow 18
// + tF/tA/tB 12 + addressing ~19) and spilled it inside the 24-step body.
// Evidence: R12/R13 at (512,3) -> implied cap ~85, compiler settled at 60
// (non-binding); R11 at (512,4) stuck at exactly 64. Fix: (512,2) -> min
// 2 blocks/CU = 4 waves/EU -> 128-reg cap; ~113 fits, no spill, and the
// RA/RB ds_read row-prefetch (pinned, one full ~336-cycle row of slack)
// plus JIT 6-deep pinned weight loads finally run as designed.
// Accumulation order unchanged -> output matches R13.

typedef float v2f __attribute__((ext_vector_type(2)));

#define B_    4
#define CIN_  32
#define COUT_ 32
#define H_    128
#define W_    128
#define HW_   (H_ * W_)
#define OUTSZ_ (B_ * COUT_ * H_ * W_)

// tab layout: [cc][tap][oc][8] = {C,S,w0,w1,w2,w3,0,0}; 294912 B
__global__ __launch_bounds__(256)
void build_wtab(const float* __restrict__ w, const float* __restrict__ wr,
                float* __restrict__ tab)
{
    int idx = blockIdx.x * 256 + threadIdx.x;   // ((cc*9+tap)<<5)|oc
    if (idx >= CIN_ * 9 * COUT_) return;        // 9216
    int oc  = idx & 31;
    int t2  = idx >> 5;
    int tap = t2 % 9;
    int cc  = t2 / 9;
    int i = tap / 3, j = tap - i * 3;
    int base = (oc * CIN_ + cc) * 9;
    float w0 = w[base + i * 3 + j];
    float w1 = w[base + (2 - j) * 3 + i];
    float w2 = w[base + (2 - i) * 3 + (2 - j)];
    float w3 = w[base + j * 3 + (2 - i)];
    float S, C;
    sincosf(wr[base + i * 3 + j], &S, &C);
    float* dst = tab + (size_t)idx * 8;
    dst[0] = C;  dst[1] = S;
    dst[2] = w0; dst[3] = w1;
    dst[4] = w2; dst[5] = w3;
    dst[6] = 0.0f; dst[7] = 0.0f;
}

#define NC_    8                      // channels staged per buffer
#define NG_    (CIN_ / NC_)           // 4 groups
#define ROWF_  68                     // floats per row = 34 pairs x 2
#define CLSTR_ (3 * ROWF_)            // 204 floats per staged channel
#define USED_  (NC_ * CLSTR_)         // 1632 slots per plane
#define PLANE_ 1636                   // plane stride (pad; 1636%32=4)
#define NBUF_  (3 * PLANE_)           // floats per buffer (f,r0,r1 planes)

struct WRow { float4 a0, a1, a2; float2 b0, b1, b2; };       // 18 floats
struct RRow { float4 f0, f1, a0, a1, b0, b1; };              // 24 floats

// Just-in-time weight row load for COMPUTED row (CCL, CII): 6 words for
// taps 3*CII..3*CII+2 of channel g*8+CCL, pinned at the step top. Base is
// per-step; imm offsets 0/+1024/+2048 B within the 13-bit signed range.
#define LOAD_W(Wd, CCL, CII) do {                                           \
    const float* _wp = wgptr + ((CCL) * 9 + (CII) * 3) * 256;               \
    (Wd).a0 = *reinterpret_cast<const float4*>(_wp);                        \
    (Wd).b0 = *reinterpret_cast<const float2*>(_wp + 4);                    \
    (Wd).a1 = *reinterpret_cast<const float4*>(_wp + 256);                  \
    (Wd).b1 = *reinterpret_cast<const float2*>(_wp + 260);                  \
    (Wd).a2 = *reinterpret_cast<const float4*>(_wp + 512);                  \
    (Wd).b2 = *reinterpret_cast<const float2*>(_wp + 516);                  \
    __builtin_amdgcn_sched_group_barrier(0x020, 6, 0); /* 6 VMEM reads */   \
} while (0)

// Load one LDS row (6 x ds_read_b128) into an RRow, pinned at issue point.
#define RLOAD(Rd, RB_, CL, II) do {                                         \
    const float* _rp = (RB_) + (CL) * CLSTR_ + (II) * ROWF_ + (p << 1);     \
    (Rd).f0 = *reinterpret_cast<const float4*>(_rp);                        \
    (Rd).f1 = *reinterpret_cast<const float4*>(_rp + 4);                    \
    (Rd).a0 = *reinterpret_cast<const float4*>(_rp + PLANE_);               \
    (Rd).a1 = *reinterpret_cast<const float4*>(_rp + PLANE_ + 4);           \
    (Rd).b0 = *reinterpret_cast<const float4*>(_rp + 2 * PLANE_);           \
    (Rd).b1 = *reinterpret_cast<const float4*>(_rp + 2 * PLANE_ + 4);       \
    __builtin_amdgcn_sched_group_barrier(0x100, 6, 0); /* 6 DS reads */     \
} while (0)

#define CORE_TAP(W4, W2, JJ) do {                                           \
    v2f _C2  = {(W4).x, (W4).x};                                            \
    v2f _S2  = {(W4).y, (W4).y};                                            \
    v2f _w0  = {(W4).z, (W4).z};                                            \
    v2f _w1  = {(W4).w, (W4).w};                                            \
    v2f _w2  = {(W2).x, (W2).x};                                            \
    v2f _w3  = {(W2).y, (W2).y};                                            \
    _Pragma("unroll")                                                       \
    for (int _q = 0; _q < 2; ++_q) {                                        \
        v2f _f  = _fP[_q + (JJ)];                                           \
        v2f _r0 = _aP[_q + (JJ)];                                           \
        v2f _r1 = _bP[_q + (JJ)];                                           \
        v2f _m1 = _S2 * _r1;                                                \
        v2f _u  = __builtin_elementwise_fma(_C2, _r0, _m1);                 \
        v2f _m2 = _S2 * _r0;                                                \
        v2f _vv = __builtin_elementwise_fma(_C2, _r1, -_m2);                \
        v2f _g0 = __builtin_elementwise_max(_u,  (v2f)(0.0f));              \
        v2f _g1 = __builtin_elementwise_max(_vv, (v2f)(0.0f));              \
        v2f _t0 = _f * _g0;                                                 \
        v2f _t1 = _f * _g1;                                                 \
        v2f _t2 = __builtin_elementwise_fma(_f, -_u,  _t0);                 \
        v2f _t3 = __builtin_elementwise_fma(_f, -_vv, _t1);                 \
        acc[_q][0] = __builtin_elementwise_fma(_t0, _w0, acc[_q][0]);       \
        acc[_q][1] = __builtin_elementwise_fma(_t1, _w1, acc[_q][1]);       \
        acc[_q][2] = __builtin_elementwise_fma(_t2, _w2, acc[_q][2]);       \
        acc[_q][3] = __builtin_elementwise_fma(_t3, _w3, acc[_q][3]);       \
    }                                                                       \
} while (0)

#define COMPUTE_R(Wr, Rs) do {                                              \
    v2f _fP[4] = {{(Rs).f0.x,(Rs).f0.y},{(Rs).f0.z,(Rs).f0.w},              \
                  {(Rs).f1.x,(Rs).f1.y},{(Rs).f1.z,(Rs).f1.w}};             \
    v2f _aP[4] = {{(Rs).a0.x,(Rs).a0.y},{(Rs).a0.z,(Rs).a0.w},              \
                  {(Rs).a1.x,(Rs).a1.y},{(Rs).a1.z,(Rs).a1.w}};             \
    v2f _bP[4] = {{(Rs).b0.x,(Rs).b0.y},{(Rs).b0.z,(Rs).b0.w},              \
                  {(Rs).b1.x,(Rs).b1.y},{(Rs).b1.z,(Rs).b1.w}};             \
    CORE_TAP((Wr).a0, (Wr).b0, 0);                                          \
    CORE_TAP((Wr).a1, (Wr).b1, 1);                                          \
    CORE_TAP((Wr).a2, (Wr).b2, 2);                                          \
} while (0)

// STEP: JIT-load this step's weights, prefetch NEXT row (LCL,LII) into Rld,
// compute CURRENT row (CCL,CII) from Ruse.
#define STEP(Rld, Ruse, LCL, LII, CCL, CII) do {                            \
    WRow _W;                                                                \
    LOAD_W(_W, CCL, CII);                                                   \
    RLOAD(Rld, cur, LCL, LII);                                              \
    COMPUTE_R(_W, Ruse);                                                    \
} while (0)

#define STEP_LAST(Ruse) do {                                                \
    WRow _W;                                                                \
    LOAD_W(_W, 7, 2);                                                       \
    COMPUTE_R(_W, Ruse);                                                    \
} while (0)

// Issue the 12 global loads for group GI into tF/tA/tB (in flight across a
// full compute phase before STAGE_WRITE consumes them).
#define STAGE_LOAD(GI) do {                                                 \
    const int _gb = chanBase + (GI) * (NC_ * HW_);                          \
    const float* _fb = f  + _gb;                                            \
    const float* _ab = r0 + _gb;                                            \
    const float* _bb = r1 + _gb;                                            \
    _Pragma("unroll")                                                       \
    for (int _k = 0; _k < 3; ++_k) {                                        \
        tF[_k] = _fb[goff[_k]]; tA[_k] = _ab[goff[_k]]; tB[_k] = _bb[goff[_k]]; \
    }                                                                       \
    if (have3) { tF[3] = _fb[goff[3]]; tA[3] = _ab[goff[3]]; tB[3] = _bb[goff[3]]; } \
} while (0)

// Masked ds_write of the staged group; slot index recomputed (tid + k*512),
// OOB-halo lanes write 0 via cndmask on okbits.
#define STAGE_WRITE(DST) do {                                               \
    float* _d = (DST);                                                      \
    _Pragma("unroll")                                                       \
    for (int _k = 0; _k < 3; ++_k) {                                        \
        const int _s = tid + (_k << 9);                                     \
        const bool _ok = (okbits >> _k) & 1;                                \
        _d[             _s] = _ok ? tF[_k] : 0.0f;                          \
        _d[PLANE_     + _s] = _ok ? tA[_k] : 0.0f;                          \
        _d[2 * PLANE_ + _s] = _ok ? tB[_k] : 0.0f;                          \
    }                                                                       \
    if (have3) {                                                            \
        const int _s = tid + 1536;                                          \
        const bool _ok = (okbits >> 3) & 1;                                 \
        _d[             _s] = _ok ? tF[3] : 0.0f;                           \
        _d[PLANE_     + _s] = _ok ? tA[3] : 0.0f;                           \
        _d[2 * PLANE_ + _s] = _ok ? tB[3] : 0.0f;                           \
    }                                                                       \
} while (0)

__global__ __launch_bounds__(512, 2)
void orient_conv_kernel(const float* __restrict__ f,
                        const float* __restrict__ r0,
                        const float* __restrict__ r1,
                        const float* __restrict__ tab,
                        float* __restrict__ out)
{
    // Double-buffered: planes 0=f, 1=r0, 2=r1 per buffer. Within plane:
    // [cl(8)][row(3)][pairslot(68)]; pairslot = c01*2 + s holds col c01+32*s.
    __shared__ float sm[2 * NBUF_];    // 39264 B

    const int tid   = threadIdx.x;
    const int oc    = tid & 31;
    const int pxg   = tid >> 5;            // 0..15
    const int p     = pxg << 1;            // even pair index 0..30
    // XCD-aware bijective swizzle: 8 XCDs, nwg=1024, 1024%8==0.
    const int obid  = blockIdx.x;
    const int bid   = (obid & 7) * ((B_ * H_ * 2) >> 3) + (obid >> 3);
    const int b     = bid >> 8;
    const int rem   = bid & 255;
    const int h     = rem >> 1;
    const int wbase = (rem & 1) << 6;      // 0 or 64

    // ---- staging descriptors: per-lane global offset + validity bits ----
    int      goff[4];
    unsigned okbits = 0;
#pragma unroll
    for (int k = 0; k < 4; ++k) {
        int s = tid + (k << 9);
        int ok = 0, go = 0;
        if (s < USED_) {
            int cl  = s / CLSTR_;
            int r2  = s - cl * CLSTR_;
            int row = r2 / ROWF_;
            int q2  = r2 - row * ROWF_;     // 0..67
            int col = (q2 >> 1) + ((q2 & 1) << 5);   // c01 + 32*s -> 0..65
            int gh = h + row - 1;
            int gw = wbase + col - 1;
            ok = ((unsigned)gh < (unsigned)H_) & ((unsigned)gw < (unsigned)W_);
            go = ok ? (cl * HW_ + gh * W_ + gw) : 0;
        }
        goff[k] = go;
        okbits |= (unsigned)ok << k;
    }
    const bool have3 = tid < 96;           // round-3 slots 1536..1631
    const int chanBase = b * (CIN_ * HW_);

    v2f acc[2][4];                     // [pair q][orient]; elems = px, px+32
#pragma unroll
    for (int q = 0; q < 2; ++q)
#pragma unroll
        for (int o = 0; o < 4; ++o) acc[q][o] = (v2f)(0.0f);

    // ---- prologue staging: g0 -> buf0; g1 loads in flight ----
    float tF[4], tA[4], tB[4];
    STAGE_LOAD(0);
    STAGE_WRITE(sm);                   // vmcnt covered by data dependence
    STAGE_LOAD(1);
    __syncthreads();

#pragma unroll 1
    for (int g = 0; g < NG_; ++g) {
        const float* cur = sm + (g & 1) * NBUF_;
        const float* wgptr = tab + (size_t)oc * 8 + (size_t)g * (NC_ * 9 * 256);
        RRow RA, RB;

        RLOAD(RA, cur, 0, 0);          // first row of this group

        // ---- 24 row-steps; R ping-pongs one row ahead, W loads JIT ----
        STEP(RB, RA, 0, 1, 0, 0);
        STEP(RA, RB, 0, 2, 0, 1);
        STEP(RB, RA, 1, 0, 0, 2);
        STEP(RA, RB, 1, 1, 1, 0);
        STEP(RB, RA, 1, 2, 1, 1);
        STEP(RA, RB, 2, 0, 1, 2);
        STEP(RB, RA, 2, 1, 2, 0);
        STEP(RA, RB, 2, 2, 2, 1);
        STEP(RB, RA, 3, 0, 2, 2);
        STEP(RA, RB, 3, 1, 3, 0);
        STEP(RB, RA, 3, 2, 3, 1);
        STEP(RA, RB, 4, 0, 3, 2);
        STEP(RB, RA, 4, 1, 4, 0);
        STEP(RA, RB, 4, 2, 4, 1);
        STEP(RB, RA, 5, 0, 4, 2);
        STEP(RA, RB, 5, 1, 5, 0);
        STEP(RB, RA, 5, 2, 5, 1);
        STEP(RA, RB, 6, 0, 5, 2);
        STEP(RB, RA, 6, 1, 6, 0);
        STEP(RA, RB, 6, 2, 6, 1);
        STEP(RB, RA, 7, 0, 6, 2);
        STEP(RA, RB, 7, 1, 7, 0);
        STEP(RB, RA, 7, 2, 7, 1);
        STEP_LAST(RB);

        // ---- stage group g+1 into the other buffer, prefetch g+2 ----
        if (g + 1 < NG_) {
            float* wbuf = sm + ((g + 1) & 1) * NBUF_;
            STAGE_WRITE(wbuf);         // waits on loads issued one phase ago
            if (g + 2 < NG_) STAGE_LOAD(g + 2);
            __syncthreads();           // one barrier per group (4 total)
        }
    }

    // ---- epilogue: max/argmax over orientations (first-max tie-break) ----
    const float cosv[4] = {1.0f, -4.37113883e-08f, -1.0f, 1.19248806e-08f};
    const float sinv[4] = {0.0f, 1.0f, -8.74227766e-08f, -1.0f};
#pragma unroll
    for (int q = 0; q < 2; ++q) {
#pragma unroll
        for (int k = 0; k < 2; ++k) {
            int wcol = wbase + p + q + (k << 5);
            float a0 = acc[q][0][k], a1 = acc[q][1][k];
            float a2 = acc[q][2][k], a3 = acc[q][3][k];
            float best = a0; int bi = 0;
            if (a1 > best) { best = a1; bi = 1; }
            if (a2 > best) { best = a2; bi = 2; }
            if (a3 > best) { best = a3; bi = 3; }
            size_t o = ((size_t)(b * COUT_ + oc) * H_ + h) * W_ + wcol;
            out[o]              = best;
            out[o + OUTSZ_]     = cosv[bi];
            out[o + 2 * OUTSZ_] = sinv[bi];
        }
    }
}

extern "C" void kernel_launch(void* const* d_in, const int* in_sizes, int n_in,
                              void* d_out, int out_size, void* d_ws, size_t ws_size,
                              hipStream_t stream)
{
    const float* f  = (const float*)d_in[0];
    const float* r0 = (const float*)d_in[1];
    const float* r1 = (const float*)d_in[2];
    const float* w  = (const float*)d_in[3];
    const float* wr = (const float*)d_in[4];
    float* out = (float*)d_out;
    float* tab = (float*)d_ws;    // 294912 B

    build_wtab<<<dim3(36), dim3(256), 0, stream>>>(w, wr, tab);
    orient_conv_kernel<<<dim3(B_ * H_ * 2), dim3(512), 0, stream>>>(
        f, r0, r1, tab, out);
}